// Round 7
// baseline (373.498 us; speedup 1.0000x reference)
//
#include <hip/hip_runtime.h>
#include <math.h>

#define TT    512
#define BB    512
#define HID   32
#define EMB   32
#define FFD   16
#define NCLS  7
#define VOCABN 1000

__device__ __forceinline__ float rl(float v, int k) {
    return __int_as_float(__builtin_amdgcn_readlane(__float_as_int(v), k));
}
__device__ __forceinline__ float fast_rcp(float x) {
#if defined(__has_builtin)
#if __has_builtin(__builtin_amdgcn_rcpf)
    return __builtin_amdgcn_rcpf(x);
#else
    return 1.0f / x;
#endif
#else
    return 1.0f / x;
#endif
}
__device__ __forceinline__ float sigf(float x) { return fast_rcp(1.0f + __expf(-x)); }
__device__ __forceinline__ float tanh_fast(float x) { return 2.0f * sigf(2.0f * x) - 1.0f; }

// ---- old-layout table (fallback path): tab[v][j] = {row j, row j+64} ----
__global__ __launch_bounds__(64) void build_xg(
    const float* __restrict__ emb, const float* __restrict__ W_ih,
    const float* __restrict__ b_ih, const float* __restrict__ b_hh,
    float2* __restrict__ tab)
{
    const int v = blockIdx.x;
    const int j = threadIdx.x;
    const float* e  = emb + v * EMB;
    const float* w0 = W_ih + j * EMB;
    const float* w1 = W_ih + (j + 64) * EMB;
    float a0 = b_ih[j]      + b_hh[j];
    float a1 = b_ih[j + 64] + b_hh[j + 64];
    #pragma unroll
    for (int k = 0; k < EMB; ++k) {
        const float ek = e[k];
        a0 = fmaf(w0[k], ek, a0);
        a1 = fmaf(w1[k], ek, a1);
    }
    tab[v * 64 + j] = make_float2(a0, a1);
}

// ---- new-layout table: tab4[v][m] = {i,f,g,o rows m,m+32,m+64,m+96} ----
__global__ __launch_bounds__(64) void build_xg4(
    const float* __restrict__ emb, const float* __restrict__ W_ih,
    const float* __restrict__ b_ih, const float* __restrict__ b_hh,
    float4* __restrict__ tab4)
{
    const int v = blockIdx.x;
    const int j = threadIdx.x;
    __shared__ float g[128];
    const float* e  = emb + v * EMB;
    const float* w0 = W_ih + j * EMB;
    const float* w1 = W_ih + (j + 64) * EMB;
    float a0 = b_ih[j]      + b_hh[j];
    float a1 = b_ih[j + 64] + b_hh[j + 64];
    #pragma unroll
    for (int k = 0; k < EMB; ++k) {
        const float ek = e[k];
        a0 = fmaf(w0[k], ek, a0);
        a1 = fmaf(w1[k], ek, a1);
    }
    g[j] = a0; g[j + 64] = a1;
    __syncthreads();
    if (j < 32)
        tab4[v * 32 + j] = make_float4(g[j], g[j + 32], g[j + 64], g[j + 96]);
}

// Serial recurrence, 2 chains per wave. Lanes 0-31: chain 2*blk, lanes 32-63:
// chain 2*blk+1. Lane (half,m) owns gate rows m,m+32,m+64,m+96 of its chain:
// i,f,g,o all lane-local -> NO shfl_xor, no half-redundant compute. h broadcast
// per-half via 32 ds_bpermute (addr (lane&32)*4 + 4k; const folds to DS offset).
// One dwordx4 tab load per step serves both chains; x columns adjacent -> one
// s_load_dwordx2. t=0 runs the normal body (h=0 => dot adds nothing).
__global__ __launch_bounds__(64, 1) void lstm_rec2(
    const int* __restrict__ x, const float4* __restrict__ tab4,
    const float* __restrict__ W_hh, float* __restrict__ hsout)
{
    const int blk  = blockIdx.x;       // chains 2*blk, 2*blk+1
    const int lane = threadIdx.x;
    const int m    = lane & 31;
    const int b0   = 2 * blk;
    const int base4 = (lane & 32) * 4; // byte base of this half for bpermute

    __shared__ float sh[8 * 64];

    // ---- weights: rows m, m+32, m+64, m+96 (same for both halves) ----
    float wI[HID], wF[HID], wG[HID], wO[HID];
    #pragma unroll
    for (int k = 0; k < HID; k += 4) {
        *(float4*)&wI[k] = *(const float4*)(W_hh + (m     ) * HID + k);
        *(float4*)&wF[k] = *(const float4*)(W_hh + (m + 32) * HID + k);
        *(float4*)&wG[k] = *(const float4*)(W_hh + (m + 64) * HID + k);
        *(float4*)&wO[k] = *(const float4*)(W_hh + (m + 96) * HID + k);
    }

    float h = 0.f, c = 0.f;

    auto tabload = [&](int v0, int v1) -> float4 {
        const int v = (lane < 32) ? v0 : v1;
        return tab4[v * 32 + m];
    };

    // ---- pipeline: tab 2 deep, x (token pairs) 4 deep ----
    int2 xvA = *(const int2*)(x + 2 * BB + b0);   // tokens for t+2
    int2 xvB = *(const int2*)(x + 3 * BB + b0);   // tokens for t+3
    int2 xv0 = *(const int2*)(x + 0 * BB + b0);
    int2 xv1 = *(const int2*)(x + 1 * BB + b0);
    float4 xg  = tabload(xv0.x, xv0.y);           // t=0
    float4 xg1 = tabload(xv1.x, xv1.y);           // t=1

    for (int t8 = 0; t8 < TT / 8; ++t8) {
        #pragma unroll
        for (int u = 0; u < 8; ++u) {
            const int t = t8 * 8 + u;
            // prefetch tab for t+2, token pair for t+4
            float4 xg2 = tabload(xvA.x, xvA.y);
            const int tn = (t + 4 < TT) ? (t + 4) : (TT - 1);
            const int2 xnew = *(const int2*)(x + tn * BB + b0);

            // per-half broadcast of h: hs[k] = h from lane (half*32 + k)
            const int hb = __float_as_int(h);
            float hs[HID];
            #pragma unroll
            for (int k = 0; k < HID; ++k)
                hs[k] = __int_as_float(__builtin_amdgcn_ds_bpermute(base4 + 4 * k, hb));

            // 4 row-dots, 8 independent FMA chains of 16
            float i0 = xg.x, i1 = 0.f, f0 = xg.y, f1 = 0.f;
            float g0 = xg.z, g1 = 0.f, o0 = xg.w, o1 = 0.f;
            #pragma unroll
            for (int k = 0; k < HID; k += 2) {
                i0 = fmaf(wI[k], hs[k], i0); i1 = fmaf(wI[k+1], hs[k+1], i1);
                f0 = fmaf(wF[k], hs[k], f0); f1 = fmaf(wF[k+1], hs[k+1], f1);
                g0 = fmaf(wG[k], hs[k], g0); g1 = fmaf(wG[k+1], hs[k+1], g1);
                o0 = fmaf(wO[k], hs[k], o0); o1 = fmaf(wO[k+1], hs[k+1], o1);
            }
            const float gi = sigf(i0 + i1);
            const float gf = sigf(f0 + f1);
            const float gg = tanh_fast(g0 + g1);
            const float go = sigf(o0 + o1);
            c = fmaf(gf, c, gi * gg);
            h = go * tanh_fast(c);

            sh[u * 64 + lane] = h;    // chain0 in [u][0:32), chain1 in [u][32:64)
            xg = xg1; xg1 = xg2; xvA = xvB; xvB = xnew;
        }
        // flush 8 steps x 2 chains: 2 x (ds_read_b128 + dwordx4 store) per lane
        {
            const int e  = lane * 4;
            const int u  = e >> 5, k0 = e & 31;
            const float4 v0 = *(const float4*)(sh + u * 64 + k0);
            const float4 v1 = *(const float4*)(sh + u * 64 + 32 + k0);
            *(float4*)(hsout + ((size_t)b0       * TT + t8 * 8) * HID + e) = v0;
            *(float4*)(hsout + ((size_t)(b0 + 1) * TT + t8 * 8) * HID + e) = v1;
        }
    }
}

// FF + logits + softmax-over-t, one block per b, 2 timesteps per thread.
__global__ __launch_bounds__(256) void ff_softmax(
    const float* __restrict__ hs,
    const float* __restrict__ W1, const float* __restrict__ b1,
    const float* __restrict__ W2, const float* __restrict__ b2,
    float* __restrict__ out)
{
    const int b    = blockIdx.x;
    const int tid  = threadIdx.x;
    const int lane = tid & 63, wv = tid >> 6;
    const int t0   = tid * 2;

    __shared__ float redM[4][NCLS];
    __shared__ float redS[4][NCLS];

    float4 hv[16];
    const float4* hb = (const float4*)(hs + ((size_t)b * TT + t0) * HID);
    #pragma unroll
    for (int q = 0; q < 16; ++q) hv[q] = hb[q];

    float lg[2][NCLS];
    #pragma unroll
    for (int r = 0; r < 2; ++r) {
        const float* hr = (const float*)(hv + 8 * r);
        float z[FFD];
        #pragma unroll
        for (int f = 0; f < FFD; ++f) {
            float a = b1[f];
            #pragma unroll
            for (int k = 0; k < HID; ++k) a = fmaf(W1[f * HID + k], hr[k], a);
            z[f] = fmaxf(a, 0.f);
        }
        #pragma unroll
        for (int cc = 0; cc < NCLS; ++cc) {
            float a = b2[cc];
            #pragma unroll
            for (int f = 0; f < FFD; ++f) a = fmaf(W2[cc * FFD + f], z[f], a);
            lg[r][cc] = a;
        }
    }

    float M[NCLS], S[NCLS];
    #pragma unroll
    for (int cc = 0; cc < NCLS; ++cc) {
        float mm = fmaxf(lg[0][cc], lg[1][cc]);
        #pragma unroll
        for (int off = 32; off; off >>= 1) mm = fmaxf(mm, __shfl_xor(mm, off));
        if (lane == 0) redM[wv][cc] = mm;
    }
    __syncthreads();
    #pragma unroll
    for (int cc = 0; cc < NCLS; ++cc)
        M[cc] = fmaxf(fmaxf(redM[0][cc], redM[1][cc]), fmaxf(redM[2][cc], redM[3][cc]));

    #pragma unroll
    for (int cc = 0; cc < NCLS; ++cc) {
        float ss = __expf(lg[0][cc] - M[cc]) + __expf(lg[1][cc] - M[cc]);
        #pragma unroll
        for (int off = 32; off; off >>= 1) ss += __shfl_xor(ss, off);
        if (lane == 0) redS[wv][cc] = ss;
    }
    __syncthreads();
    #pragma unroll
    for (int cc = 0; cc < NCLS; ++cc)
        S[cc] = (redS[0][cc] + redS[1][cc]) + (redS[2][cc] + redS[3][cc]);

    #pragma unroll
    for (int r = 0; r < 2; ++r) {
        float* o = out + ((size_t)(t0 + r) * BB + b) * NCLS;
        #pragma unroll
        for (int cc = 0; cc < NCLS; ++cc)
            o[cc] = __expf(lg[r][cc] - M[cc]) * fast_rcp(S[cc]);
    }
}

// ---------------- round-2 verified fused kernel (fallback paths) ----------------
template <bool TAB>
__global__ __launch_bounds__(64) void lstm_all(
    const int* __restrict__ x, const float* __restrict__ emb,
    const float* __restrict__ W_ih, const float* __restrict__ W_hh,
    const float* __restrict__ b_ih, const float* __restrict__ b_hh,
    const float* __restrict__ W1, const float* __restrict__ b1,
    const float* __restrict__ W2, const float* __restrict__ b2,
    const float2* __restrict__ tab, float* __restrict__ out)
{
    const int b  = blockIdx.x;
    const int j  = threadIdx.x;
    const int m  = j & 31;
    const bool lo = j < 32;
    const int rA = j, rB = j + 64;

    float whhA[HID], whhB[HID];
    #pragma unroll
    for (int k = 0; k < HID; k += 4) {
        float4 a;
        a = *(const float4*)(W_hh + rA * HID + k); whhA[k]=a.x; whhA[k+1]=a.y; whhA[k+2]=a.z; whhA[k+3]=a.w;
        a = *(const float4*)(W_hh + rB * HID + k); whhB[k]=a.x; whhB[k+1]=a.y; whhB[k+2]=a.z; whhB[k+3]=a.w;
    }
    float wihA[HID], wihB[HID];
    float biasA = 0.f, biasB = 0.f;
    if constexpr (!TAB) {
        #pragma unroll
        for (int k = 0; k < HID; k += 4) {
            float4 a;
            a = *(const float4*)(W_ih + rA * HID + k); wihA[k]=a.x; wihA[k+1]=a.y; wihA[k+2]=a.z; wihA[k+3]=a.w;
            a = *(const float4*)(W_ih + rB * HID + k); wihB[k]=a.x; wihB[k+1]=a.y; wihB[k+2]=a.z; wihB[k+3]=a.w;
        }
        biasA = b_ih[rA] + b_hh[rA];
        biasB = b_ih[rB] + b_hh[rB];
    }
    const int f16 = j & 15;
    float w1r[HID];
    #pragma unroll
    for (int k = 0; k < HID; ++k) w1r[k] = W1[f16 * HID + k];
    const int cls = j & 7;
    const int c7  = (cls < NCLS) ? cls : 0;
    float w2r[FFD];
    #pragma unroll
    for (int f = 0; f < FFD; ++f) w2r[f] = W2[c7 * FFD + f];
    const float b1v = b1[f16];
    const float b2v = b2[c7];

    float h = 0.f, c = 0.f;
    float mrun = -3.0e38f, srun = 0.f;

    auto gates = [&](float accA, float accB) {
        const float actA = sigf(accA);
        const float sB   = lo ? 2.0f * accB : accB;
        const float sgB  = sigf(sB);
        const float actB = lo ? 2.0f * sgB - 1.0f : sgB;
        const float oA = __shfl_xor(actA, 32);
        const float oB = __shfl_xor(actB, 32);
        const float gi = lo ? actA : oA;
        const float gf = lo ? oA   : actA;
        const float gg = lo ? actB : oB;
        const float go = lo ? oB   : actB;
        c = fmaf(gf, c, gi * gg);
        h = go * tanh_fast(c);
    };

    auto ff_head = [&](int t_out, const float* hsv) {
        float z0 = b1v, z1 = 0.f;
        #pragma unroll
        for (int k = 0; k < HID; k += 2) {
            z0 = fmaf(w1r[k],     hsv[k],     z0);
            z1 = fmaf(w1r[k + 1], hsv[k + 1], z1);
        }
        const float z = fmaxf(z0 + z1, 0.0f);
        float lgv = b2v;
        #pragma unroll
        for (int f = 0; f < FFD; ++f) lgv = fmaf(w2r[f], rl(z, f), lgv);
        const float mn = fmaxf(mrun, lgv);
        srun = fmaf(srun, __expf(mrun - mn), __expf(lgv - mn));
        mrun = mn;
        if (j < NCLS) out[(t_out * BB + b) * NCLS + j] = lgv;
    };

    int xvn1 = x[1 * BB + b];
    int xvn2 = x[2 * BB + b];
    float2 xg = make_float2(0.f, 0.f);
    float eA = 0.f;
    if constexpr (TAB) xg = tab[(size_t)x[b] * 64 + j];
    else               eA = emb[x[b] * EMB + m];

    if constexpr (TAB) {
        gates(xg.x, xg.y);
    } else {
        float es[EMB];
        #pragma unroll
        for (int k = 0; k < EMB; ++k) es[k] = rl(eA, k);
        float p0 = biasA, p1 = 0.f, q0 = biasB, q1 = 0.f;
        #pragma unroll
        for (int k = 0; k < EMB; k += 2) {
            p0 = fmaf(wihA[k],   es[k],   p0); p1 = fmaf(wihA[k+1], es[k+1], p1);
            q0 = fmaf(wihB[k],   es[k],   q0); q1 = fmaf(wihB[k+1], es[k+1], q1);
        }
        gates(p0 + p1, q0 + q1);
    }
    if constexpr (TAB) xg = tab[(size_t)xvn1 * 64 + j];
    else               eA = emb[xvn1 * EMB + m];
    xvn1 = xvn2;
    xvn2 = x[3 * BB + b];

    for (int t = 1; t < TT; ++t) {
        float2 xg_n = make_float2(0.f, 0.f);
        float  e_n  = 0.f;
        if (t + 1 < TT) {
            if constexpr (TAB) xg_n = tab[(size_t)xvn1 * 64 + j];
            else               e_n  = emb[xvn1 * EMB + m];
        }
        const int xv_n3 = (t + 3 < TT) ? x[(t + 3) * BB + b] : 0;

        float hsv[HID];
        #pragma unroll
        for (int k = 0; k < HID; ++k) hsv[k] = rl(h, k);

        ff_head(t - 1, hsv);

        float p0, p1 = 0.f, q0, q1 = 0.f;
        if constexpr (TAB) { p0 = xg.x; q0 = xg.y; }
        else               { p0 = biasA; q0 = biasB; }
        if constexpr (!TAB) {
            float es[EMB];
            #pragma unroll
            for (int k = 0; k < EMB; ++k) es[k] = rl(eA, k);
            #pragma unroll
            for (int k = 0; k < EMB; k += 2) {
                p0 = fmaf(wihA[k],   es[k],   p0); p1 = fmaf(wihA[k+1], es[k+1], p1);
                q0 = fmaf(wihB[k],   es[k],   q0); q1 = fmaf(wihB[k+1], es[k+1], q1);
            }
        }
        #pragma unroll
        for (int k = 0; k < HID; k += 2) {
            p0 = fmaf(whhA[k],   hsv[k],   p0); p1 = fmaf(whhA[k+1], hsv[k+1], p1);
            q0 = fmaf(whhB[k],   hsv[k],   q0); q1 = fmaf(whhB[k+1], hsv[k+1], q1);
        }
        gates(p0 + p1, q0 + q1);

        xg = xg_n; eA = e_n; xvn1 = xvn2; xvn2 = xv_n3;
    }

    {
        float hsv[HID];
        #pragma unroll
        for (int k = 0; k < HID; ++k) hsv[k] = rl(h, k);
        ff_head(TT - 1, hsv);
    }

    #pragma unroll 1
    for (int cc = 0; cc < NCLS; ++cc) {
        const float mc = rl(mrun, cc);
        const float sc = rl(srun, cc);
        const float ic = 1.0f / sc;
        #pragma unroll
        for (int i = 0; i < TT / 64; ++i) {
            const int t = j + 64 * i;
            const int a = (t * BB + b) * NCLS + cc;
            out[a] = __expf(out[a] - mc) * ic;
        }
    }
}

extern "C" void kernel_launch(void* const* d_in, const int* in_sizes, int n_in,
                              void* d_out, int out_size, void* d_ws, size_t ws_size,
                              hipStream_t stream) {
    const int*   x   = (const int*)  d_in[0];
    const float* emb = (const float*)d_in[1];
    const float* Wih = (const float*)d_in[2];
    const float* Whh = (const float*)d_in[3];
    const float* bih = (const float*)d_in[4];
    const float* bhh = (const float*)d_in[5];
    const float* W1  = (const float*)d_in[6];
    const float* b1  = (const float*)d_in[7];
    const float* W2  = (const float*)d_in[8];
    const float* b2  = (const float*)d_in[9];
    float* out = (float*)d_out;

    const size_t tab_bytes = (size_t)VOCABN * 128 * sizeof(float);   // 512 000
    const size_t hs_off    = 524288;                                 // 512 KiB align
    const size_t hs_bytes  = (size_t)BB * TT * HID * sizeof(float);  // 32 MiB
    if (ws_size >= hs_off + hs_bytes) {
        float4* tab4 = (float4*)d_ws;
        float*  hs   = (float*)((char*)d_ws + hs_off);
        build_xg4<<<VOCABN, 64, 0, stream>>>(emb, Wih, bih, bhh, tab4);
        lstm_rec2<<<BB / 2, 64, 0, stream>>>(x, tab4, Whh, hs);
        ff_softmax<<<BB, 256, 0, stream>>>(hs, W1, b1, W2, b2, out);
    } else if (ws_size >= tab_bytes) {
        float2* tab = (float2*)d_ws;
        build_xg<<<VOCABN, 64, 0, stream>>>(emb, Wih, bih, bhh, tab);
        lstm_all<true><<<BB, 64, 0, stream>>>(x, emb, Wih, Whh, bih, bhh,
                                              W1, b1, W2, b2, tab, out);
    } else {
        lstm_all<false><<<BB, 64, 0, stream>>>(x, emb, Wih, Whh, bih, bhh,
                                               W1, b1, W2, b2, nullptr, out);
    }
}

// Round 8
// 301.242 us; speedup vs baseline: 1.2399x; 1.2399x over previous
//
#include <hip/hip_runtime.h>
#include <math.h>

#define TT    512
#define BB    512
#define HID   32
#define EMB   32
#define FFD   16
#define NCLS  7
#define VOCABN 1000

__device__ __forceinline__ float rl(float v, int k) {
    return __int_as_float(__builtin_amdgcn_readlane(__float_as_int(v), k));
}
__device__ __forceinline__ float fast_rcp(float x) {
#if defined(__has_builtin)
#if __has_builtin(__builtin_amdgcn_rcpf)
    return __builtin_amdgcn_rcpf(x);
#else
    return 1.0f / x;
#endif
#else
    return 1.0f / x;
#endif
}
__device__ __forceinline__ float sigf(float x) { return fast_rcp(1.0f + __expf(-x)); }
__device__ __forceinline__ float tanh_fast(float x) { return 2.0f * sigf(2.0f * x) - 1.0f; }

// xg_table[v][j] = {W_ih[j,:]·emb[v,:]+b[j], W_ih[j+64,:]·emb[v,:]+b[j+64]}
__global__ __launch_bounds__(64) void build_xg(
    const float* __restrict__ emb, const float* __restrict__ W_ih,
    const float* __restrict__ b_ih, const float* __restrict__ b_hh,
    float2* __restrict__ tab)
{
    const int v = blockIdx.x;
    const int j = threadIdx.x;
    const float* e  = emb + v * EMB;
    const float* w0 = W_ih + j * EMB;
    const float* w1 = W_ih + (j + 64) * EMB;
    float a0 = b_ih[j]      + b_hh[j];
    float a1 = b_ih[j + 64] + b_hh[j + 64];
    #pragma unroll
    for (int k = 0; k < EMB; ++k) {
        const float ek = e[k];
        a0 = fmaf(w0[k], ek, a0);
        a1 = fmaf(w1[k], ek, a1);
    }
    tab[v * 64 + j] = make_float2(a0, a1);
}

// Serial recurrence ONLY. One wave per chain (512 waves).
// Round-7 diagnosis: at VGPR_Count=44 the compiler REMATERIALIZES the 64
// weight floats from L1 every step (16x global_load_dwordx4 = 16 KB/step/wave
// ~= 256 cyc/step of L1 drain on the critical path). Asm pins don't stop it
// (allocator may spill/remat after the asm site). Fix: VOLATILE scalar loads
// -- a volatile load cannot legally be re-executed, so the 64 values must
// stay live across the loop. __launch_bounds__(64,1): full VGPR budget.
__global__ __launch_bounds__(64, 1) void lstm_rec(
    const int* __restrict__ x, const float2* __restrict__ tab,
    const float* __restrict__ W_hh, float* __restrict__ hsout)
{
    const int b  = blockIdx.x;
    const int j  = threadIdx.x;
    const int m  = j & 31;
    const bool lo = j < 32;

    __shared__ float sh[8 * HID];

    // ---- W_hh rows j and j+64 -> registers via volatile loads (no remat) ----
    float whhA[HID], whhB[HID];
    {
        const volatile float* ra = W_hh + j * HID;
        const volatile float* rb = W_hh + (j + 64) * HID;
        #pragma unroll
        for (int k = 0; k < HID; ++k) { whhA[k] = ra[k]; whhB[k] = rb[k]; }
    }
    #define PIN16(A, base) \
        asm volatile("" : "+v"((A)[(base)+0]), "+v"((A)[(base)+1]), "+v"((A)[(base)+2]), "+v"((A)[(base)+3]), \
                          "+v"((A)[(base)+4]), "+v"((A)[(base)+5]), "+v"((A)[(base)+6]), "+v"((A)[(base)+7]), \
                          "+v"((A)[(base)+8]), "+v"((A)[(base)+9]), "+v"((A)[(base)+10]), "+v"((A)[(base)+11]), \
                          "+v"((A)[(base)+12]), "+v"((A)[(base)+13]), "+v"((A)[(base)+14]), "+v"((A)[(base)+15]))
    PIN16(whhA, 0); PIN16(whhA, 16);
    PIN16(whhB, 0); PIN16(whhB, 16);
    #undef PIN16

    float h = 0.f, c = 0.f;
    float* hrow0 = hsout + (size_t)b * TT * HID;

    // ---- pipeline: tab 2 deep, x 4 deep (x addrs wave-uniform -> s_load) ----
    int xc = x[2 * BB + b], xd = x[3 * BB + b];
    float2 xg  = tab[(size_t)x[b] * 64 + j];            // t=0
    float2 xg1 = tab[(size_t)x[1 * BB + b] * 64 + j];   // t=1

    for (int t8 = 0; t8 < TT / 8; ++t8) {
        #pragma unroll
        for (int u = 0; u < 8; ++u) {
            const int t = t8 * 8 + u;
            float2 xg2 = tab[(size_t)xc * 64 + j];
            const int tn = (t + 4 < TT) ? (t + 4) : (TT - 1);
            const int xnew = x[tn * BB + b];

            // broadcast h -> 32 uniform values (SGPRs)
            float hs[HID];
            #pragma unroll
            for (int k = 0; k < HID; ++k) hs[k] = rl(h, k);

            // dot: 4 chains of 16
            float p0 = xg.x, p1 = 0.f, q0 = xg.y, q1 = 0.f;
            #pragma unroll
            for (int k = 0; k < HID; k += 2) {
                p0 = fmaf(whhA[k],   hs[k],   p0); p1 = fmaf(whhA[k+1], hs[k+1], p1);
                q0 = fmaf(whhB[k],   hs[k],   q0); q1 = fmaf(whhB[k+1], hs[k+1], q1);
            }
            const float accA = p0 + p1, accB = q0 + q1;

            // lanes<32: accA->i (sig), accB->g (tanh); lanes>=32: accA->f, accB->o
            const float actA = sigf(accA);
            const float sB   = lo ? 2.0f * accB : accB;
            const float sgB  = sigf(sB);
            const float actB = lo ? 2.0f * sgB - 1.0f : sgB;
            const float oA = __shfl_xor(actA, 32);
            const float oB = __shfl_xor(actB, 32);
            const float gi = lo ? actA : oA;
            const float gf = lo ? oA   : actA;
            const float gg = lo ? actB : oB;
            const float go = lo ? oB   : actB;
            c = fmaf(gf, c, gi * gg);
            h = go * tanh_fast(c);

            if (lo) sh[u * HID + m] = h;     // LDS stage (no vmcnt)
            xg = xg1; xg1 = xg2; xc = xd; xd = xnew;
        }
        // flush 8 steps: 256 floats, one float4 per lane, coalesced 1KB store
        const float4 v = *(const float4*)(sh + j * 4);
        *(float4*)(hrow0 + t8 * 8 * HID + j * 4) = v;
    }
}

// FF + logits + softmax-over-t, one block per b, 2 timesteps per thread.
__global__ __launch_bounds__(256) void ff_softmax(
    const float* __restrict__ hs,
    const float* __restrict__ W1, const float* __restrict__ b1,
    const float* __restrict__ W2, const float* __restrict__ b2,
    float* __restrict__ out)
{
    const int b    = blockIdx.x;
    const int tid  = threadIdx.x;
    const int lane = tid & 63, wv = tid >> 6;
    const int t0   = tid * 2;

    __shared__ float redM[4][NCLS];
    __shared__ float redS[4][NCLS];

    float4 hv[16];
    const float4* hb = (const float4*)(hs + ((size_t)b * TT + t0) * HID);
    #pragma unroll
    for (int q = 0; q < 16; ++q) hv[q] = hb[q];

    float lg[2][NCLS];
    #pragma unroll
    for (int r = 0; r < 2; ++r) {
        const float* hr = (const float*)(hv + 8 * r);
        float z[FFD];
        #pragma unroll
        for (int f = 0; f < FFD; ++f) {
            float a = b1[f];
            #pragma unroll
            for (int k = 0; k < HID; ++k) a = fmaf(W1[f * HID + k], hr[k], a);
            z[f] = fmaxf(a, 0.f);
        }
        #pragma unroll
        for (int cc = 0; cc < NCLS; ++cc) {
            float a = b2[cc];
            #pragma unroll
            for (int f = 0; f < FFD; ++f) a = fmaf(W2[cc * FFD + f], z[f], a);
            lg[r][cc] = a;
        }
    }

    float M[NCLS], S[NCLS];
    #pragma unroll
    for (int cc = 0; cc < NCLS; ++cc) {
        float mm = fmaxf(lg[0][cc], lg[1][cc]);
        #pragma unroll
        for (int off = 32; off; off >>= 1) mm = fmaxf(mm, __shfl_xor(mm, off));
        if (lane == 0) redM[wv][cc] = mm;
    }
    __syncthreads();
    #pragma unroll
    for (int cc = 0; cc < NCLS; ++cc)
        M[cc] = fmaxf(fmaxf(redM[0][cc], redM[1][cc]), fmaxf(redM[2][cc], redM[3][cc]));

    #pragma unroll
    for (int cc = 0; cc < NCLS; ++cc) {
        float ss = __expf(lg[0][cc] - M[cc]) + __expf(lg[1][cc] - M[cc]);
        #pragma unroll
        for (int off = 32; off; off >>= 1) ss += __shfl_xor(ss, off);
        if (lane == 0) redS[wv][cc] = ss;
    }
    __syncthreads();
    #pragma unroll
    for (int cc = 0; cc < NCLS; ++cc)
        S[cc] = (redS[0][cc] + redS[1][cc]) + (redS[2][cc] + redS[3][cc]);

    #pragma unroll
    for (int r = 0; r < 2; ++r) {
        float* o = out + ((size_t)(t0 + r) * BB + b) * NCLS;
        #pragma unroll
        for (int cc = 0; cc < NCLS; ++cc)
            o[cc] = __expf(lg[r][cc] - M[cc]) * fast_rcp(S[cc]);
    }
}

// ---------------- round-2 verified fused kernel (fallback paths) ----------------
template <bool TAB>
__global__ __launch_bounds__(64) void lstm_all(
    const int* __restrict__ x, const float* __restrict__ emb,
    const float* __restrict__ W_ih, const float* __restrict__ W_hh,
    const float* __restrict__ b_ih, const float* __restrict__ b_hh,
    const float* __restrict__ W1, const float* __restrict__ b1,
    const float* __restrict__ W2, const float* __restrict__ b2,
    const float2* __restrict__ tab, float* __restrict__ out)
{
    const int b  = blockIdx.x;
    const int j  = threadIdx.x;
    const int m  = j & 31;
    const bool lo = j < 32;
    const int rA = j, rB = j + 64;

    float whhA[HID], whhB[HID];
    #pragma unroll
    for (int k = 0; k < HID; k += 4) {
        float4 a;
        a = *(const float4*)(W_hh + rA * HID + k); whhA[k]=a.x; whhA[k+1]=a.y; whhA[k+2]=a.z; whhA[k+3]=a.w;
        a = *(const float4*)(W_hh + rB * HID + k); whhB[k]=a.x; whhB[k+1]=a.y; whhB[k+2]=a.z; whhB[k+3]=a.w;
    }
    float wihA[HID], wihB[HID];
    float biasA = 0.f, biasB = 0.f;
    if constexpr (!TAB) {
        #pragma unroll
        for (int k = 0; k < HID; k += 4) {
            float4 a;
            a = *(const float4*)(W_ih + rA * HID + k); wihA[k]=a.x; wihA[k+1]=a.y; wihA[k+2]=a.z; wihA[k+3]=a.w;
            a = *(const float4*)(W_ih + rB * HID + k); wihB[k]=a.x; wihB[k+1]=a.y; wihB[k+2]=a.z; wihB[k+3]=a.w;
        }
        biasA = b_ih[rA] + b_hh[rA];
        biasB = b_ih[rB] + b_hh[rB];
    }
    const int f16 = j & 15;
    float w1r[HID];
    #pragma unroll
    for (int k = 0; k < HID; ++k) w1r[k] = W1[f16 * HID + k];
    const int cls = j & 7;
    const int c7  = (cls < NCLS) ? cls : 0;
    float w2r[FFD];
    #pragma unroll
    for (int f = 0; f < FFD; ++f) w2r[f] = W2[c7 * FFD + f];
    const float b1v = b1[f16];
    const float b2v = b2[c7];

    float h = 0.f, c = 0.f;
    float mrun = -3.0e38f, srun = 0.f;

    auto gates = [&](float accA, float accB) {
        const float actA = sigf(accA);
        const float sB   = lo ? 2.0f * accB : accB;
        const float sgB  = sigf(sB);
        const float actB = lo ? 2.0f * sgB - 1.0f : sgB;
        const float oA = __shfl_xor(actA, 32);
        const float oB = __shfl_xor(actB, 32);
        const float gi = lo ? actA : oA;
        const float gf = lo ? oA   : actA;
        const float gg = lo ? actB : oB;
        const float go = lo ? oB   : actB;
        c = fmaf(gf, c, gi * gg);
        h = go * tanh_fast(c);
    };

    auto ff_head = [&](int t_out, const float* hsv) {
        float z0 = b1v, z1 = 0.f;
        #pragma unroll
        for (int k = 0; k < HID; k += 2) {
            z0 = fmaf(w1r[k],     hsv[k],     z0);
            z1 = fmaf(w1r[k + 1], hsv[k + 1], z1);
        }
        const float z = fmaxf(z0 + z1, 0.0f);
        float lgv = b2v;
        #pragma unroll
        for (int f = 0; f < FFD; ++f) lgv = fmaf(w2r[f], rl(z, f), lgv);
        const float mn = fmaxf(mrun, lgv);
        srun = fmaf(srun, __expf(mrun - mn), __expf(lgv - mn));
        mrun = mn;
        if (j < NCLS) out[(t_out * BB + b) * NCLS + j] = lgv;
    };

    int xvn1 = x[1 * BB + b];
    int xvn2 = x[2 * BB + b];
    float2 xg = make_float2(0.f, 0.f);
    float eA = 0.f;
    if constexpr (TAB) xg = tab[(size_t)x[b] * 64 + j];
    else               eA = emb[x[b] * EMB + m];

    if constexpr (TAB) {
        gates(xg.x, xg.y);
    } else {
        float es[EMB];
        #pragma unroll
        for (int k = 0; k < EMB; ++k) es[k] = rl(eA, k);
        float p0 = biasA, p1 = 0.f, q0 = biasB, q1 = 0.f;
        #pragma unroll
        for (int k = 0; k < EMB; k += 2) {
            p0 = fmaf(wihA[k],   es[k],   p0); p1 = fmaf(wihA[k+1], es[k+1], p1);
            q0 = fmaf(wihB[k],   es[k],   q0); q1 = fmaf(wihB[k+1], es[k+1], q1);
        }
        gates(p0 + p1, q0 + q1);
    }
    if constexpr (TAB) xg = tab[(size_t)xvn1 * 64 + j];
    else               eA = emb[xvn1 * EMB + m];
    xvn1 = xvn2;
    xvn2 = x[3 * BB + b];

    for (int t = 1; t < TT; ++t) {
        float2 xg_n = make_float2(0.f, 0.f);
        float  e_n  = 0.f;
        if (t + 1 < TT) {
            if constexpr (TAB) xg_n = tab[(size_t)xvn1 * 64 + j];
            else               e_n  = emb[xvn1 * EMB + m];
        }
        const int xv_n3 = (t + 3 < TT) ? x[(t + 3) * BB + b] : 0;

        float hsv[HID];
        #pragma unroll
        for (int k = 0; k < HID; ++k) hsv[k] = rl(h, k);

        ff_head(t - 1, hsv);

        float p0, p1 = 0.f, q0, q1 = 0.f;
        if constexpr (TAB) { p0 = xg.x; q0 = xg.y; }
        else               { p0 = biasA; q0 = biasB; }
        if constexpr (!TAB) {
            float es[EMB];
            #pragma unroll
            for (int k = 0; k < EMB; ++k) es[k] = rl(eA, k);
            #pragma unroll
            for (int k = 0; k < EMB; k += 2) {
                p0 = fmaf(wihA[k],   es[k],   p0); p1 = fmaf(wihA[k+1], es[k+1], p1);
                q0 = fmaf(wihB[k],   es[k],   q0); q1 = fmaf(wihB[k+1], es[k+1], q1);
            }
        }
        #pragma unroll
        for (int k = 0; k < HID; k += 2) {
            p0 = fmaf(whhA[k],   hsv[k],   p0); p1 = fmaf(whhA[k+1], hsv[k+1], p1);
            q0 = fmaf(whhB[k],   hsv[k],   q0); q1 = fmaf(whhB[k+1], hsv[k+1], q1);
        }
        gates(p0 + p1, q0 + q1);

        xg = xg_n; eA = e_n; xvn1 = xvn2; xvn2 = xv_n3;
    }

    {
        float hsv[HID];
        #pragma unroll
        for (int k = 0; k < HID; ++k) hsv[k] = rl(h, k);
        ff_head(TT - 1, hsv);
    }

    #pragma unroll 1
    for (int cc = 0; cc < NCLS; ++cc) {
        const float mc = rl(mrun, cc);
        const float sc = rl(srun, cc);
        const float ic = 1.0f / sc;
        #pragma unroll
        for (int i = 0; i < TT / 64; ++i) {
            const int t = j + 64 * i;
            const int a = (t * BB + b) * NCLS + cc;
            out[a] = __expf(out[a] - mc) * ic;
        }
    }
}

extern "C" void kernel_launch(void* const* d_in, const int* in_sizes, int n_in,
                              void* d_out, int out_size, void* d_ws, size_t ws_size,
                              hipStream_t stream) {
    const int*   x   = (const int*)  d_in[0];
    const float* emb = (const float*)d_in[1];
    const float* Wih = (const float*)d_in[2];
    const float* Whh = (const float*)d_in[3];
    const float* bih = (const float*)d_in[4];
    const float* bhh = (const float*)d_in[5];
    const float* W1  = (const float*)d_in[6];
    const float* b1  = (const float*)d_in[7];
    const float* W2  = (const float*)d_in[8];
    const float* b2  = (const float*)d_in[9];
    float* out = (float*)d_out;

    const size_t tab_bytes = (size_t)VOCABN * 128 * sizeof(float);   // 512 000
    const size_t hs_off    = 524288;                                 // 512 KiB align
    const size_t hs_bytes  = (size_t)BB * TT * HID * sizeof(float);  // 32 MiB
    if (ws_size >= hs_off + hs_bytes) {
        float2* tab = (float2*)d_ws;
        float*  hs  = (float*)((char*)d_ws + hs_off);
        build_xg<<<VOCABN, 64, 0, stream>>>(emb, Wih, bih, bhh, tab);
        lstm_rec<<<BB, 64, 0, stream>>>(x, tab, Whh, hs);
        ff_softmax<<<BB, 256, 0, stream>>>(hs, W1, b1, W2, b2, out);
    } else if (ws_size >= tab_bytes) {
        float2* tab = (float2*)d_ws;
        build_xg<<<VOCABN, 64, 0, stream>>>(emb, Wih, bih, bhh, tab);
        lstm_all<true><<<BB, 64, 0, stream>>>(x, emb, Wih, Whh, bih, bhh,
                                              W1, b1, W2, b2, tab, out);
    } else {
        lstm_all<false><<<BB, 64, 0, stream>>>(x, emb, Wih, Whh, bih, bhh,
                                               W1, b1, W2, b2, nullptr, out);
    }
}